// Round 20
// baseline (86.902 us; speedup 1.0000x reference)
//
#include <hip/hip_runtime.h>

// dist[pix, o] = ||x[pix]||^2 + ||omega[o]||^2 - 2 * x.omega
// M = 262144 pixels, O = 256 protos, D = 64.
// Round-20: EXACT round-19 structure (coalesced LDS-staged x, omega in regs,
// 32x32 MFMA, full-line scalar stores, nt loads, plain stores, triple-buffer
// + raw lgkmcnt barrier, stores decoupled from barrier). Single change:
// HALF THE RESIDENT WAVES. NBLOCKS 1024->512, ITERS 8->16 (512 pix/block).
// Evidence: fill sustains 7 TB/s at ~3.4 waves/CU; writes favor fewer
// concurrent streams per channel (longer row hits, fewer turnarounds).
// We ran 16 waves/CU; now 8. Compute <10% of budget and loads prefetched
// 2 iters ahead, so latency hiding should survive. Also amortizes the
// omega prologue 2x.

typedef __attribute__((ext_vector_type(4))) float f32x4;
typedef __attribute__((ext_vector_type(16))) float f32x16;
typedef __attribute__((ext_vector_type(8))) short s16x8;

constexpr int D_ = 64;
constexpr int O_ = 256;
constexpr int M_ = 16 * 128 * 128;                  // 262144
constexpr int ITERS = 16;
constexpr int PIX_PER_ITER = 32;
constexpr int PIX_PER_BLOCK = ITERS * PIX_PER_ITER; // 512
constexpr int NBLOCKS = M_ / PIX_PER_BLOCK;         // 512
constexpr int LROW = 68;   // padded LDS row stride (floats)

__device__ __forceinline__ unsigned short f2bf(float f) {
    // round-to-nearest-even fp32 -> bf16
    unsigned u = __builtin_bit_cast(unsigned, f);
    u += 0x7FFFu + ((u >> 16) & 1u);
    return (unsigned short)(u >> 16);
}

// raw barrier: LDS visibility only (lgkmcnt), NO vmcnt drain
#define LDS_BARRIER() do {                                        \
    asm volatile("s_waitcnt lgkmcnt(0)" ::: "memory");            \
    __builtin_amdgcn_sched_barrier(0);                            \
    __builtin_amdgcn_s_barrier();                                 \
    __builtin_amdgcn_sched_barrier(0);                            \
} while (0)

__global__ __launch_bounds__(256, 4) void dist_kernel(
    const float* __restrict__ x,
    const float* __restrict__ om,
    float* __restrict__ out)
{
    __shared__ float xstg[3][32 * LROW];   // 3 x 8704 B = 26112 B

    const int tid  = threadIdx.x;
    const int wave = tid >> 6;
    const int lane = tid & 63;
    const int p    = lane & 31;   // A: pixel row ; B: proto col ; store col
    const int h    = lane >> 5;   // k-half

    // ---------- omega -> per-wave register fragments (+ p2) -----------------
    s16x8 Bf0[4], Bf1[4];
    float p2r0 = 0.f, p2r1 = 0.f;
#pragma unroll
    for (int tt = 0; tt < 2; ++tt) {
        const int T = wave * 2 + tt;
        float p2p = 0.f;
#pragma unroll
        for (int s = 0; s < 4; ++s) {
            const float* src = om + (T * 32 + p) * D_ + s * 16 + h * 8;
            f32x4 v0 = *(const f32x4*)(src);
            f32x4 v1 = *(const f32x4*)(src + 4);
            s16x8 f;
#pragma unroll
            for (int j = 0; j < 4; ++j) {
                f[j]     = (short)f2bf(v0[j]); p2p += v0[j] * v0[j];
                f[4 + j] = (short)f2bf(v1[j]); p2p += v1[j] * v1[j];
            }
            if (tt == 0) Bf0[s] = f; else Bf1[s] = f;
        }
        p2p += __shfl_xor(p2p, 32);
        if (tt == 0) p2r0 = p2p; else p2r1 = p2p;
    }

    // ---------- staging geometry -------------------------------------------
    const size_t gbase = (size_t)blockIdx.x * PIX_PER_BLOCK * D_;
    const int sr = tid >> 4;              // staging row 0..15
    const int sc = (tid & 15) * 4;        // staging col (floats)

    // prologue: commit tile0, preload tile1 into set B
    f32x4 nva0, nva1, nvb0, nvb1;
    {
        const float* s0 = x + gbase + tid * 4;
        f32x4 t0 = __builtin_nontemporal_load((const f32x4*)(s0));
        f32x4 t1 = __builtin_nontemporal_load((const f32x4*)(s0 + 1024));
        const float* s1 = x + gbase + 2048 + tid * 4;
        nvb0 = __builtin_nontemporal_load((const f32x4*)(s1));
        nvb1 = __builtin_nontemporal_load((const f32x4*)(s1 + 1024));
        *(f32x4*)&xstg[0][sr * LROW + sc] = t0;
        *(f32x4*)&xstg[0][(16 + sr) * LROW + sc] = t1;
    }
    __syncthreads();   // prologue only

#pragma unroll 4
    for (int it = 0; it < ITERS; ++it) {
        const int rbase = blockIdx.x * PIX_PER_BLOCK + it * PIX_PER_ITER;

        // ---- issue loads for tile it+2 into set (it&1): A=even, B=odd ----
        if (it + 2 < ITERS) {
            const float* s = x + gbase + (size_t)(it + 2) * (PIX_PER_ITER * D_) + tid * 4;
            if ((it & 1) == 0) {
                nva0 = __builtin_nontemporal_load((const f32x4*)(s));
                nva1 = __builtin_nontemporal_load((const f32x4*)(s + 1024));
            } else {
                nvb0 = __builtin_nontemporal_load((const f32x4*)(s));
                nvb1 = __builtin_nontemporal_load((const f32x4*)(s + 1024));
            }
        }

        // ---- A-frags from LDS + exact ||x||^2 ----
        const float* row = &xstg[it % 3][p * LROW + h * 8];
        s16x8 Af[4];
        float x2p = 0.f;
#pragma unroll
        for (int s = 0; s < 4; ++s) {
            f32x4 a0 = *(const f32x4*)(row + s * 16);
            f32x4 a1 = *(const f32x4*)(row + s * 16 + 4);
#pragma unroll
            for (int j = 0; j < 4; ++j) {
                Af[s][j]     = (short)f2bf(a0[j]); x2p += a0[j] * a0[j];
                Af[s][4 + j] = (short)f2bf(a1[j]); x2p += a1[j] * a1[j];
            }
        }
        x2p += __shfl_xor(x2p, 32);

        // ---- MFMA: the wave's 2 proto-tiles ----
        f32x16 acc0 = {0.f, 0.f, 0.f, 0.f, 0.f, 0.f, 0.f, 0.f,
                       0.f, 0.f, 0.f, 0.f, 0.f, 0.f, 0.f, 0.f};
        f32x16 acc1 = acc0;
#pragma unroll
        for (int s = 0; s < 4; ++s) {
            acc0 = __builtin_amdgcn_mfma_f32_32x32x16_bf16(Af[s], Bf0[s], acc0, 0, 0, 0);
            acc1 = __builtin_amdgcn_mfma_f32_32x32x16_bf16(Af[s], Bf1[s], acc1, 0, 0, 0);
        }

        // ---- commit tile it+1 (loaded 1 iter ago, set (it+1)&1) ----
        if (it + 1 < ITERS) {
            float* dst = &xstg[(it + 1) % 3][0];
            if (((it + 1) & 1) == 0) {
                *(f32x4*)&dst[sr * LROW + sc] = nva0;
                *(f32x4*)&dst[(16 + sr) * LROW + sc] = nva1;
            } else {
                *(f32x4*)&dst[sr * LROW + sc] = nvb0;
                *(f32x4*)&dst[(16 + sr) * LROW + sc] = nvb1;
            }
            LDS_BARRIER();   // lgkmcnt only — stores stay in flight
        }

        // ---- stores AFTER the barrier (R13 geometry, plain dword) ----
        const int T0 = wave * 2;
        float* const ob0 = out + (size_t)(rbase + 4 * h) * O_ + T0 * 32 + p;
#pragma unroll
        for (int reg = 0; reg < 16; ++reg) {
            const int r = (reg & 3) + 8 * (reg >> 2);
            const float x2v = __shfl(x2p, r + 4 * h);
            ob0[(size_t)r * O_]      = (x2v + p2r0) - 2.f * acc0[reg];
            ob0[(size_t)r * O_ + 32] = (x2v + p2r1) - 2.f * acc1[reg];
        }
    }
}

extern "C" void kernel_launch(void* const* d_in, const int* in_sizes, int n_in,
                              void* d_out, int out_size, void* d_ws, size_t ws_size,
                              hipStream_t stream) {
    const float* x  = (const float*)d_in[0];   // [16,128,128,64] fp32
    const float* om = (const float*)d_in[1];   // [256,64] fp32
    float* out = (float*)d_out;                // [16,128,128,256,1] fp32

    dist_kernel<<<dim3(NBLOCKS), dim3(256), 0, stream>>>(x, om, out);
}

// Round 21
// 64.382 us; speedup vs baseline: 1.3498x; 1.3498x over previous
//
#include <hip/hip_runtime.h>

// dist[pix, o] = ||x[pix]||^2 + ||omega[o]||^2 - 2 * x.omega
// M = 262144 pixels, O = 256 protos, D = 64.
// Round-21: R19 base (32x32x16 MFMA A=x/B=omega-in-regs, full-line scalar
// stores, plain stores, triple-buffered staging, stores decoupled from
// barriers). Single change: staging via __builtin_amdgcn_global_load_lds
// (DMA straight to LDS): removes the 8-way-conflicted ds_write commit and
// the global->VGPR->LDS hop. LDS dest must be linear, so the per-lane GLOBAL
// source is pre-swizzled (XOR within each 256B row: word c' = c ^ 8*(row&7));
// every 128B line is still fully covered per instruction -> same request
// count. ds_read applies the same XOR (4-way conflict, same as the old
// padded layout). Completion is vmcnt-tracked -> hand-counted s_waitcnt
// vmcnt(N) at each barrier (N = exact in-order FIFO count: 32 stores + 2
// staging loads in flight), so stores keep flying across barriers.

typedef __attribute__((ext_vector_type(4))) float f32x4;
typedef __attribute__((ext_vector_type(16))) float f32x16;
typedef __attribute__((ext_vector_type(8))) short s16x8;

constexpr int D_ = 64;
constexpr int O_ = 256;
constexpr int M_ = 16 * 128 * 128;                  // 262144
constexpr int ITERS = 8;
constexpr int PIX_PER_ITER = 32;
constexpr int PIX_PER_BLOCK = ITERS * PIX_PER_ITER; // 256
constexpr int NBLOCKS = M_ / PIX_PER_BLOCK;         // 1024

__device__ __forceinline__ unsigned short f2bf(float f) {
    // round-to-nearest-even fp32 -> bf16
    unsigned u = __builtin_bit_cast(unsigned, f);
    u += 0x7FFFu + ((u >> 16) & 1u);
    return (unsigned short)(u >> 16);
}

__global__ __launch_bounds__(256, 4) void dist_kernel(
    const float* __restrict__ x,
    const float* __restrict__ om,
    float* __restrict__ out)
{
    __shared__ float xstg[3][2048];   // 3 x 8 KiB, LINEAR (global_load_lds dest)

    const int tid  = threadIdx.x;
    const int wave = tid >> 6;
    const int lane = tid & 63;
    const int p    = lane & 31;   // A: pixel row ; B: proto col ; store col
    const int h    = lane >> 5;   // k-half

    // ---------- omega -> per-wave register fragments (+ p2) -----------------
    s16x8 Bf0[4], Bf1[4];
    float p2r0 = 0.f, p2r1 = 0.f;
#pragma unroll
    for (int tt = 0; tt < 2; ++tt) {
        const int T = wave * 2 + tt;
        float p2p = 0.f;
#pragma unroll
        for (int s = 0; s < 4; ++s) {
            const float* src = om + (T * 32 + p) * D_ + s * 16 + h * 8;
            f32x4 v0 = *(const f32x4*)(src);
            f32x4 v1 = *(const f32x4*)(src + 4);
            s16x8 f;
#pragma unroll
            for (int j = 0; j < 4; ++j) {
                f[j]     = (short)f2bf(v0[j]); p2p += v0[j] * v0[j];
                f[4 + j] = (short)f2bf(v1[j]); p2p += v1[j] * v1[j];
            }
            if (tt == 0) Bf0[s] = f; else Bf1[s] = f;
        }
        p2p += __shfl_xor(p2p, 32);
        if (tt == 0) p2r0 = p2p; else p2r1 = p2p;
    }

    // ---------- staging: DMA global->LDS, pre-swizzled source ---------------
    const size_t gbase = (size_t)blockIdx.x * PIX_PER_BLOCK * D_;

    // x word (row r, col c) lives at LDS word r*64 + (c ^ 8*(r&7)).
    // Loader: LDS word W (linear, lane*4) <- x word r*64 + ((W&63) ^ 8*(r&7)).
    auto stage = [&](int tile, int buf) {
#pragma unroll
        for (int k = 0; k < 2; ++k) {
            const int r = wave * 8 + k * 4 + (lane >> 4);         // row in tile
            const int c = ((lane & 15) * 4) ^ (8 * (r & 7));      // swizzled col
            const float* src = x + gbase + (size_t)tile * (PIX_PER_ITER * D_)
                                 + r * 64 + c;
            __builtin_amdgcn_global_load_lds(
                (const __attribute__((address_space(1))) unsigned int*)(const void*)src,
                (__attribute__((address_space(3))) unsigned int*)(void*)
                    &xstg[buf][wave * 512 + k * 256],
                16, 0, 2 /* NT */);
        }
    };

    // prologue: issue tiles 0 and 1; wait tile 0 (2 younger ops allowed)
    stage(0, 0);
    stage(1, 1);
    asm volatile("s_waitcnt vmcnt(2)" ::: "memory");
    __builtin_amdgcn_sched_barrier(0);
    __builtin_amdgcn_s_barrier();
    __builtin_amdgcn_sched_barrier(0);

#pragma unroll
    for (int it = 0; it < ITERS; ++it) {
        const int rbase = blockIdx.x * PIX_PER_BLOCK + it * PIX_PER_ITER;

        // ---- issue DMA for tile it+2 ----
        if (it + 2 < ITERS) stage(it + 2, (it + 2) % 3);

        // ---- A-frags from LDS (swizzled read) + exact ||x||^2 ----
        const float* rowb = &xstg[it % 3][p * 64];
        const int xm = 8 * (p & 7);
        s16x8 Af[4];
        float x2p = 0.f;
#pragma unroll
        for (int s = 0; s < 4; ++s) {
            const int idx = (h * 8 + s * 16) ^ xm;
            f32x4 a0 = *(const f32x4*)&rowb[idx];
            f32x4 a1 = *(const f32x4*)&rowb[idx + 4];
#pragma unroll
            for (int j = 0; j < 4; ++j) {
                Af[s][j]     = (short)f2bf(a0[j]); x2p += a0[j] * a0[j];
                Af[s][4 + j] = (short)f2bf(a1[j]); x2p += a1[j] * a1[j];
            }
        }
        x2p += __shfl_xor(x2p, 32);

        // ---- MFMA: the wave's 2 proto-tiles ----
        f32x16 acc0 = {0.f, 0.f, 0.f, 0.f, 0.f, 0.f, 0.f, 0.f,
                       0.f, 0.f, 0.f, 0.f, 0.f, 0.f, 0.f, 0.f};
        f32x16 acc1 = acc0;
#pragma unroll
        for (int s = 0; s < 4; ++s) {
            acc0 = __builtin_amdgcn_mfma_f32_32x32x16_bf16(Af[s], Bf0[s], acc0, 0, 0, 0);
            acc1 = __builtin_amdgcn_mfma_f32_32x32x16_bf16(Af[s], Bf1[s], acc1, 0, 0, 0);
        }

        // ---- barrier: ensure tile it+1's DMA landed; stores stay in flight.
        // Counted vmcnt: ops issued after stage(it+1) =
        //   it==0 : stage(it+2)=2 (no stores yet)            -> vmcnt(2)
        //   1..ITERS-3 : stores(it-1)=32 + stage(it+2)=2     -> vmcnt(34)
        //   it==ITERS-2: stores(it-1)=32, no more staging    -> vmcnt(32)
        //   it==ITERS-1: no barrier needed
        if (it + 1 < ITERS) {
            if (it == 0)             asm volatile("s_waitcnt vmcnt(2)"  ::: "memory");
            else if (it + 2 < ITERS) asm volatile("s_waitcnt vmcnt(34)" ::: "memory");
            else                     asm volatile("s_waitcnt vmcnt(32)" ::: "memory");
            asm volatile("s_waitcnt lgkmcnt(0)" ::: "memory");
            __builtin_amdgcn_sched_barrier(0);
            __builtin_amdgcn_s_barrier();
            __builtin_amdgcn_sched_barrier(0);
        }

        // ---- stores AFTER the barrier (R13 geometry, plain dword) ----
        const int T0 = wave * 2;
        float* const ob0 = out + (size_t)(rbase + 4 * h) * O_ + T0 * 32 + p;
#pragma unroll
        for (int reg = 0; reg < 16; ++reg) {
            const int r = (reg & 3) + 8 * (reg >> 2);
            const float x2v = __shfl(x2p, r + 4 * h);
            ob0[(size_t)r * O_]      = (x2v + p2r0) - 2.f * acc0[reg];
            ob0[(size_t)r * O_ + 32] = (x2v + p2r1) - 2.f * acc1[reg];
        }
    }
}

extern "C" void kernel_launch(void* const* d_in, const int* in_sizes, int n_in,
                              void* d_out, int out_size, void* d_ws, size_t ws_size,
                              hipStream_t stream) {
    const float* x  = (const float*)d_in[0];   // [16,128,128,64] fp32
    const float* om = (const float*)d_in[1];   // [256,64] fp32
    float* out = (float*)d_out;                // [16,128,128,256,1] fp32

    dist_kernel<<<dim3(NBLOCKS), dim3(256), 0, stream>>>(x, om, out);
}

// Round 22
// 63.671 us; speedup vs baseline: 1.3649x; 1.0112x over previous
//
#include <hip/hip_runtime.h>

// dist[pix, o] = ||x[pix]||^2 + ||omega[o]||^2 - 2 * x.omega
// M = 262144 pixels, O = 256 protos, D = 64.
// Round-22: R21 base (DMA global->LDS staging, omega-in-regs, 32x32 MFMA,
// full-line scalar stores, counted-vmcnt barriers, stores fly across
// barriers). Two changes:
// (1) swizzle granularity 32B -> 16B: word c' = c ^ 4*(r&15). R21's 8-word
//     XOR left ds_reads on 4 bank-slots = 16-way conflict; 4-word XOR gives
//     8 slots -> 64 lanes over all 32 banks = 2-way = free. DMA source still
//     covers each 64B granule completely within one instruction (in-granule
//     lane permutation merges in the coalescer).
//     Read addressing: x words base..base+7 live at (base^xm)+0..3 and
//     ((base^xm)^4)+0..3, xm = 4*(p&15)  [base mult of 8 -> base+4 = base^4].
// (2) tile-0/1 DMA issued BEFORE the omega prologue: in-order vmcnt means
//     waiting on (younger) omega loads implies DMA landed -> staging latency
//     fully hidden under omega load+convert.

typedef __attribute__((ext_vector_type(4))) float f32x4;
typedef __attribute__((ext_vector_type(16))) float f32x16;
typedef __attribute__((ext_vector_type(8))) short s16x8;

constexpr int D_ = 64;
constexpr int O_ = 256;
constexpr int M_ = 16 * 128 * 128;                  // 262144
constexpr int ITERS = 8;
constexpr int PIX_PER_ITER = 32;
constexpr int PIX_PER_BLOCK = ITERS * PIX_PER_ITER; // 256
constexpr int NBLOCKS = M_ / PIX_PER_BLOCK;         // 1024

__device__ __forceinline__ unsigned short f2bf(float f) {
    // round-to-nearest-even fp32 -> bf16
    unsigned u = __builtin_bit_cast(unsigned, f);
    u += 0x7FFFu + ((u >> 16) & 1u);
    return (unsigned short)(u >> 16);
}

__global__ __launch_bounds__(256, 4) void dist_kernel(
    const float* __restrict__ x,
    const float* __restrict__ om,
    float* __restrict__ out)
{
    __shared__ float xstg[3][2048];   // 3 x 8 KiB, LINEAR (global_load_lds dest)

    const int tid  = threadIdx.x;
    const int wave = tid >> 6;
    const int lane = tid & 63;
    const int p    = lane & 31;   // A: pixel row ; B: proto col ; store col
    const int h    = lane >> 5;   // k-half

    const size_t gbase = (size_t)blockIdx.x * PIX_PER_BLOCK * D_;

    // x word (row r, col c) lives at LDS word r*64 + (c ^ 4*(r&15)).
    auto stage = [&](int tile, int buf) {
#pragma unroll
        for (int k = 0; k < 2; ++k) {
            const int r = wave * 8 + k * 4 + (lane >> 4);         // row in tile
            const int c = ((lane & 15) * 4) ^ (4 * (r & 15));     // swizzled col
            const float* src = x + gbase + (size_t)tile * (PIX_PER_ITER * D_)
                                 + r * 64 + c;
            __builtin_amdgcn_global_load_lds(
                (const __attribute__((address_space(1))) unsigned int*)(const void*)src,
                (__attribute__((address_space(3))) unsigned int*)(void*)
                    &xstg[buf][wave * 512 + k * 256],
                16, 0, 2 /* NT */);
        }
    };

    // ---------- issue tile 0/1 DMA FIRST (hidden under omega prologue) ------
    stage(0, 0);
    stage(1, 1);

    // ---------- omega -> per-wave register fragments (+ p2) -----------------
    s16x8 Bf0[4], Bf1[4];
    float p2r0 = 0.f, p2r1 = 0.f;
#pragma unroll
    for (int tt = 0; tt < 2; ++tt) {
        const int T = wave * 2 + tt;
        float p2p = 0.f;
#pragma unroll
        for (int s = 0; s < 4; ++s) {
            const float* src = om + (T * 32 + p) * D_ + s * 16 + h * 8;
            f32x4 v0 = *(const f32x4*)(src);
            f32x4 v1 = *(const f32x4*)(src + 4);
            s16x8 f;
#pragma unroll
            for (int j = 0; j < 4; ++j) {
                f[j]     = (short)f2bf(v0[j]); p2p += v0[j] * v0[j];
                f[4 + j] = (short)f2bf(v1[j]); p2p += v1[j] * v1[j];
            }
            if (tt == 0) Bf0[s] = f; else Bf1[s] = f;
        }
        p2p += __shfl_xor(p2p, 32);
        if (tt == 0) p2r0 = p2p; else p2r1 = p2p;
    }

    // omega loads (younger) are drained by their consumers above -> tile-0/1
    // DMA (older) is complete too; wait is a formality.
    asm volatile("s_waitcnt vmcnt(2)" ::: "memory");
    __builtin_amdgcn_sched_barrier(0);
    __builtin_amdgcn_s_barrier();
    __builtin_amdgcn_sched_barrier(0);

#pragma unroll
    for (int it = 0; it < ITERS; ++it) {
        const int rbase = blockIdx.x * PIX_PER_BLOCK + it * PIX_PER_ITER;

        // ---- issue DMA for tile it+2 ----
        if (it + 2 < ITERS) stage(it + 2, (it + 2) % 3);

        // ---- A-frags from LDS (16B-swizzled read, 2-way = free) ----
        const float* rowb = &xstg[it % 3][p * 64];
        const int xm = 4 * (p & 15);
        s16x8 Af[4];
        float x2p = 0.f;
#pragma unroll
        for (int s = 0; s < 4; ++s) {
            const int i0 = (h * 8 + s * 16) ^ xm;   // words base..base+3
            f32x4 a0 = *(const f32x4*)&rowb[i0];
            f32x4 a1 = *(const f32x4*)&rowb[i0 ^ 4]; // words base+4..base+7
#pragma unroll
            for (int j = 0; j < 4; ++j) {
                Af[s][j]     = (short)f2bf(a0[j]); x2p += a0[j] * a0[j];
                Af[s][4 + j] = (short)f2bf(a1[j]); x2p += a1[j] * a1[j];
            }
        }
        x2p += __shfl_xor(x2p, 32);

        // ---- MFMA: the wave's 2 proto-tiles ----
        f32x16 acc0 = {0.f, 0.f, 0.f, 0.f, 0.f, 0.f, 0.f, 0.f,
                       0.f, 0.f, 0.f, 0.f, 0.f, 0.f, 0.f, 0.f};
        f32x16 acc1 = acc0;
#pragma unroll
        for (int s = 0; s < 4; ++s) {
            acc0 = __builtin_amdgcn_mfma_f32_32x32x16_bf16(Af[s], Bf0[s], acc0, 0, 0, 0);
            acc1 = __builtin_amdgcn_mfma_f32_32x32x16_bf16(Af[s], Bf1[s], acc1, 0, 0, 0);
        }

        // ---- barrier: tile it+1's DMA landed; stores stay in flight.
        //   it==0 : stage(it+2)=2 outstanding allowed      -> vmcnt(2)
        //   1..ITERS-3 : stores(it-1)=32 + stage(it+2)=2   -> vmcnt(34)
        //   it==ITERS-2: stores(it-1)=32, no more staging  -> vmcnt(32)
        if (it + 1 < ITERS) {
            if (it == 0)             asm volatile("s_waitcnt vmcnt(2)"  ::: "memory");
            else if (it + 2 < ITERS) asm volatile("s_waitcnt vmcnt(34)" ::: "memory");
            else                     asm volatile("s_waitcnt vmcnt(32)" ::: "memory");
            asm volatile("s_waitcnt lgkmcnt(0)" ::: "memory");
            __builtin_amdgcn_sched_barrier(0);
            __builtin_amdgcn_s_barrier();
            __builtin_amdgcn_sched_barrier(0);
        }

        // ---- stores AFTER the barrier (R13 geometry, plain dword) ----
        const int T0 = wave * 2;
        float* const ob0 = out + (size_t)(rbase + 4 * h) * O_ + T0 * 32 + p;
#pragma unroll
        for (int reg = 0; reg < 16; ++reg) {
            const int r = (reg & 3) + 8 * (reg >> 2);
            const float x2v = __shfl(x2p, r + 4 * h);
            ob0[(size_t)r * O_]      = (x2v + p2r0) - 2.f * acc0[reg];
            ob0[(size_t)r * O_ + 32] = (x2v + p2r1) - 2.f * acc1[reg];
        }
    }
}

extern "C" void kernel_launch(void* const* d_in, const int* in_sizes, int n_in,
                              void* d_out, int out_size, void* d_ws, size_t ws_size,
                              hipStream_t stream) {
    const float* x  = (const float*)d_in[0];   // [16,128,128,64] fp32
    const float* om = (const float*)d_in[1];   // [256,64] fp32
    float* out = (float*)d_out;                // [16,128,128,256,1] fp32

    dist_kernel<<<dim3(NBLOCKS), dim3(256), 0, stream>>>(x, om, out);
}

// Round 23
// 63.584 us; speedup vs baseline: 1.3667x; 1.0014x over previous
//
#include <hip/hip_runtime.h>

// dist[pix, o] = ||x[pix]||^2 + ||omega[o]||^2 - 2 * x.omega
// M = 262144 pixels, O = 256 protos, D = 64.
// Round-23: R22 base (DMA global->LDS staging w/ 16B swizzle, omega-in-regs,
// 32x32 MFMA, full-line scalar stores, counted-vmcnt barriers, stores fly
// across barriers). Single change: STAGING DEPTH 2 -> 3 tiles ahead with a
// 4-buffer rotation. The stage(it+1) wait now sits behind 68 newer VMEM ops
// (stores(it-2)+stage(it+2)+stores(it-1)+stage(it+3)) -> vmcnt(63) (field
// max; over-waits 3-5 already-old stores). Outstanding stores at each wait:
// 34 -> 63 (+85% MLP). Evidence: every prior depth increase paid
// (R18 69.5 -> R19 67.6 -> R21 64.4 -> R22 63.7); waves are parked at the
// wait >95% of the time, so queue depth is the only in-kernel lever left.
// LDS 24 -> 32 KiB, still 4 blocks/CU (128 KiB).

typedef __attribute__((ext_vector_type(4))) float f32x4;
typedef __attribute__((ext_vector_type(16))) float f32x16;
typedef __attribute__((ext_vector_type(8))) short s16x8;

constexpr int D_ = 64;
constexpr int O_ = 256;
constexpr int M_ = 16 * 128 * 128;                  // 262144
constexpr int ITERS = 8;
constexpr int PIX_PER_ITER = 32;
constexpr int PIX_PER_BLOCK = ITERS * PIX_PER_ITER; // 256
constexpr int NBLOCKS = M_ / PIX_PER_BLOCK;         // 1024

__device__ __forceinline__ unsigned short f2bf(float f) {
    // round-to-nearest-even fp32 -> bf16
    unsigned u = __builtin_bit_cast(unsigned, f);
    u += 0x7FFFu + ((u >> 16) & 1u);
    return (unsigned short)(u >> 16);
}

__global__ __launch_bounds__(256, 4) void dist_kernel(
    const float* __restrict__ x,
    const float* __restrict__ om,
    float* __restrict__ out)
{
    __shared__ float xstg[4][2048];   // 4 x 8 KiB, LINEAR (global_load_lds dest)

    const int tid  = threadIdx.x;
    const int wave = tid >> 6;
    const int lane = tid & 63;
    const int p    = lane & 31;   // A: pixel row ; B: proto col ; store col
    const int h    = lane >> 5;   // k-half

    const size_t gbase = (size_t)blockIdx.x * PIX_PER_BLOCK * D_;

    // x word (row r, col c) lives at LDS word r*64 + (c ^ 4*(r&15)).
    auto stage = [&](int tile) {
        const int buf = tile & 3;
#pragma unroll
        for (int k = 0; k < 2; ++k) {
            const int r = wave * 8 + k * 4 + (lane >> 4);         // row in tile
            const int c = ((lane & 15) * 4) ^ (4 * (r & 15));     // swizzled col
            const float* src = x + gbase + (size_t)tile * (PIX_PER_ITER * D_)
                                 + r * 64 + c;
            __builtin_amdgcn_global_load_lds(
                (const __attribute__((address_space(1))) unsigned int*)(const void*)src,
                (__attribute__((address_space(3))) unsigned int*)(void*)
                    &xstg[buf][wave * 512 + k * 256],
                16, 0, 2 /* NT */);
        }
    };

    // ---------- issue tile 0/1/2 DMA FIRST (hidden under omega prologue) ----
    stage(0);
    stage(1);
    stage(2);

    // ---------- omega -> per-wave register fragments (+ p2) -----------------
    s16x8 Bf0[4], Bf1[4];
    float p2r0 = 0.f, p2r1 = 0.f;
#pragma unroll
    for (int tt = 0; tt < 2; ++tt) {
        const int T = wave * 2 + tt;
        float p2p = 0.f;
#pragma unroll
        for (int s = 0; s < 4; ++s) {
            const float* src = om + (T * 32 + p) * D_ + s * 16 + h * 8;
            f32x4 v0 = *(const f32x4*)(src);
            f32x4 v1 = *(const f32x4*)(src + 4);
            s16x8 f;
#pragma unroll
            for (int j = 0; j < 4; ++j) {
                f[j]     = (short)f2bf(v0[j]); p2p += v0[j] * v0[j];
                f[4 + j] = (short)f2bf(v1[j]); p2p += v1[j] * v1[j];
            }
            if (tt == 0) Bf0[s] = f; else Bf1[s] = f;
        }
        p2p += __shfl_xor(p2p, 32);
        if (tt == 0) p2r0 = p2p; else p2r1 = p2p;
    }

    // need stage(0) landed; stage(1)+stage(2) may stay in flight (4 newer).
    // (omega loads are newer still; their consumers above already drained them,
    //  which in-order implies stage(0..2) are done too — wait is a guarantee.)
    asm volatile("s_waitcnt vmcnt(4)" ::: "memory");
    __builtin_amdgcn_sched_barrier(0);
    __builtin_amdgcn_s_barrier();
    __builtin_amdgcn_sched_barrier(0);

#pragma unroll
    for (int it = 0; it < ITERS; ++it) {
        const int rbase = blockIdx.x * PIX_PER_BLOCK + it * PIX_PER_ITER;

        // ---- issue DMA for tile it+3 (buf (it+3)&3 = (it-1)&3, whose readers
        //      finished at iter it-1's barrier) ----
        if (it + 3 < ITERS) stage(it + 3);

        // ---- A-frags from LDS (16B-swizzled read, 2-way = free) ----
        const float* rowb = &xstg[it & 3][p * 64];
        const int xm = 4 * (p & 15);
        s16x8 Af[4];
        float x2p = 0.f;
#pragma unroll
        for (int s = 0; s < 4; ++s) {
            const int i0 = (h * 8 + s * 16) ^ xm;    // words base..base+3
            f32x4 a0 = *(const f32x4*)&rowb[i0];
            f32x4 a1 = *(const f32x4*)&rowb[i0 ^ 4]; // words base+4..base+7
#pragma unroll
            for (int j = 0; j < 4; ++j) {
                Af[s][j]     = (short)f2bf(a0[j]); x2p += a0[j] * a0[j];
                Af[s][4 + j] = (short)f2bf(a1[j]); x2p += a1[j] * a1[j];
            }
        }
        x2p += __shfl_xor(x2p, 32);

        // ---- MFMA: the wave's 2 proto-tiles ----
        f32x16 acc0 = {0.f, 0.f, 0.f, 0.f, 0.f, 0.f, 0.f, 0.f,
                       0.f, 0.f, 0.f, 0.f, 0.f, 0.f, 0.f, 0.f};
        f32x16 acc1 = acc0;
#pragma unroll
        for (int s = 0; s < 4; ++s) {
            acc0 = __builtin_amdgcn_mfma_f32_32x32x16_bf16(Af[s], Bf0[s], acc0, 0, 0, 0);
            acc1 = __builtin_amdgcn_mfma_f32_32x32x16_bf16(Af[s], Bf1[s], acc1, 0, 0, 0);
        }

        // ---- barrier: tile it+1's DMA landed; stores stay deep in flight.
        // newer-than-stage(it+1) in FIFO:
        //   it==0: stage(2)[prologue] + stage(3) = 4                 -> vmcnt(4)
        //   it==1: stage(3) 2 + stores(0) 32 + stage(4) 2 = 36       -> vmcnt(36)
        //   else : stores(it-2) 32 + stage(it+2) 2 + stores(it-1) 32
        //          + stage(it+3) 2 = 66..68                          -> vmcnt(63)
        if (it + 1 < ITERS) {
            if (it == 0)      asm volatile("s_waitcnt vmcnt(4)"  ::: "memory");
            else if (it == 1) asm volatile("s_waitcnt vmcnt(36)" ::: "memory");
            else              asm volatile("s_waitcnt vmcnt(63)" ::: "memory");
            asm volatile("s_waitcnt lgkmcnt(0)" ::: "memory");
            __builtin_amdgcn_sched_barrier(0);
            __builtin_amdgcn_s_barrier();
            __builtin_amdgcn_sched_barrier(0);
        }

        // ---- stores AFTER the barrier (R13 geometry, plain dword) ----
        const int T0 = wave * 2;
        float* const ob0 = out + (size_t)(rbase + 4 * h) * O_ + T0 * 32 + p;
#pragma unroll
        for (int reg = 0; reg < 16; ++reg) {
            const int r = (reg & 3) + 8 * (reg >> 2);
            const float x2v = __shfl(x2p, r + 4 * h);
            ob0[(size_t)r * O_]      = (x2v + p2r0) - 2.f * acc0[reg];
            ob0[(size_t)r * O_ + 32] = (x2v + p2r1) - 2.f * acc1[reg];
        }
    }
}

extern "C" void kernel_launch(void* const* d_in, const int* in_sizes, int n_in,
                              void* d_out, int out_size, void* d_ws, size_t ws_size,
                              hipStream_t stream) {
    const float* x  = (const float*)d_in[0];   // [16,128,128,64] fp32
    const float* om = (const float*)d_in[1];   // [256,64] fp32
    float* out = (float*)d_out;                // [16,128,128,256,1] fp32

    dist_kernel<<<dim3(NBLOCKS), dim3(256), 0, stream>>>(x, om, out);
}